// Round 10
// baseline (1374.981 us; speedup 1.0000x reference)
//
#include <hip/hip_runtime.h>

#define Nn 50000
#define Ee 600000
#define Hd 128
#define Ld 4
#define Kd 3

typedef __attribute__((ext_vector_type(8))) short short8;
typedef __attribute__((ext_vector_type(4))) float float4v;

union U4 { uint4 u; short8 s; };

__device__ __forceinline__ unsigned bf16rne(float f) {
    unsigned u = __float_as_uint(f);
    return (u + 0x7fffu + ((u >> 16) & 1u)) >> 16;
}
__device__ __forceinline__ void split2(float f0, float f1, unsigned& hd, unsigned& ld) {
    unsigned h0 = bf16rne(f0), h1 = bf16rne(f1);
    float r0 = f0 - __uint_as_float(h0 << 16);
    float r1 = f1 - __uint_as_float(h1 << 16);
    unsigned l0 = bf16rne(r0), l1 = bf16rne(r1);
    hd = h0 | (h1 << 16);
    ld = l0 | (l1 << 16);
}
__device__ __forceinline__ float bf16lo(unsigned v) { return __uint_as_float(v << 16); }
__device__ __forceinline__ float bf16hi(unsigned v) { return __uint_as_float(v & 0xffff0000u); }

__global__ void zero_int_kernel(int* __restrict__ p, int n) {
    int i = blockIdx.x * blockDim.x + threadIdx.x;
    int stride = gridDim.x * blockDim.x;
    for (; i < n; i += stride) p[i] = 0;
}

__global__ void count_kernel(const int* __restrict__ col, int* __restrict__ deg) {
    int e = blockIdx.x * blockDim.x + threadIdx.x;
    if (e < Ee) atomicAdd(&deg[col[e]], 1);
}

// Shfl-based exclusive scan.
__global__ void scan_kernel(const int* __restrict__ deg, int* __restrict__ starts,
                            float* __restrict__ dinv) {
    __shared__ int wsum[16];
    __shared__ int carry_s;
    int tid = threadIdx.x;
    int lane = tid & 63, w = tid >> 6;
    if (tid == 0) carry_s = 0;
    __syncthreads();
    for (int base = 0; base < Nn; base += 1024) {
        int i = base + tid;
        int v = (i < Nn) ? deg[i] : 0;
        if (i < Nn) dinv[i] = (v > 0) ? rsqrtf((float)v) : 0.0f;
        int s = v;
#pragma unroll
        for (int off = 1; off < 64; off <<= 1) {
            int t = __shfl_up(s, off);
            if (lane >= off) s += t;
        }
        if (lane == 63) wsum[w] = s;
        __syncthreads();
        if (w == 0) {
            int ws = (lane < 16) ? wsum[lane] : 0;
#pragma unroll
            for (int off = 1; off < 16; off <<= 1) {
                int t = __shfl_up(ws, off);
                if (lane >= off) ws += t;
            }
            if (lane < 16) wsum[lane] = ws;
        }
        __syncthreads();
        int woff = (w > 0) ? wsum[w - 1] : 0;
        int carry = carry_s;
        if (i < Nn) starts[i] = carry + woff + s - v;
        __syncthreads();
        if (tid == 1023) carry_s = carry + wsum[15];
    }
    __syncthreads();
    if (threadIdx.x == 0) starts[Nn] = carry_s;
}

// CSR fill; writes ea_s (slot-ordered edge attrs) directly.
__global__ void fill_kernel(const int* __restrict__ row, const int* __restrict__ col,
                            const int* __restrict__ starts, int* __restrict__ cnt,
                            const float* __restrict__ dinv, const float* __restrict__ ea,
                            int* __restrict__ src_s, float* __restrict__ w_s,
                            float4* __restrict__ ea_s) {
    int e = blockIdx.x * blockDim.x + threadIdx.x;
    if (e < Ee) {
        int c = col[e], r = row[e];
        float4 ev = *(const float4*)&ea[(size_t)e * 4];
        int slot = starts[c] + atomicAdd(&cnt[c], 1);
        src_s[slot] = r;
        w_s[slot] = dinv[r] * dinv[c];
        ea_s[slot] = ev;
    }
}

// x [N][7] -> padded aligned xp [N][8] (pad = 0)
__global__ void xpack_kernel(const float* __restrict__ x, float* __restrict__ xp) {
    int i = blockIdx.x * blockDim.x + threadIdx.x;
    if (i < Nn) {
        float4 a = make_float4(x[i * 7], x[i * 7 + 1], x[i * 7 + 2], x[i * 7 + 3]);
        float4 b = make_float4(x[i * 7 + 4], x[i * 7 + 5], x[i * 7 + 6], 0.0f);
        *(float4*)&xp[i * 8] = a;
        *(float4*)&xp[i * 8 + 4] = b;
    }
}

// 17 weight matrices [k][n] fp32 -> FRAGMENT-SWIZZLED bf16 hi/lo planes.
__global__ void wconv_kernel(const float* __restrict__ eW2, const float* __restrict__ tagW,
                             unsigned short* __restrict__ WThi,
                             unsigned short* __restrict__ WTlo) {
    int id = blockIdx.x * blockDim.x + threadIdx.x;
    if (id >= 17 * 16384) return;
    int m = id >> 14;
    int rem = id & 16383;
    int n = rem >> 7, k = rem & 127;
    const float* src = (m == 0) ? eW2 : tagW + (size_t)(m - 1) * 16384;
    float f = src[k * Hd + n];
    unsigned h = bf16rne(f);
    float r = f - __uint_as_float(h << 16);
    int kc = k >> 5, quad = (k >> 3) & 3, j = k & 7;
    int nt = n >> 4, l15 = n & 15;
    int lane = quad * 16 + l15;
    int idx = (m << 14) + (((kc * 8 + nt) * 64) + lane) * 8 + j;
    WThi[idx] = (unsigned short)h;
    WTlo[idx] = (unsigned short)bf16rne(r);
}

// Layer-1-only edge pass (r8 form — pipeline reverted, it regressed).
__global__ __launch_bounds__(256) void edge_l1_kernel(
    const float* __restrict__ xp, const float4* __restrict__ ea_s,
    const int* __restrict__ starts, const int* __restrict__ src_s,
    const float* __restrict__ eW1, const float* __restrict__ eb1,
    float* __restrict__ tout) {
    int lane = threadIdx.x & 63;
    float w1x[18], w1y[18];
#pragma unroll
    for (int j = 0; j < 18; ++j) {
        w1x[j] = eW1[j * Hd + lane];
        w1y[j] = eW1[j * Hd + lane + 64];
    }
    float b1x = eb1[lane], b1y = eb1[lane + 64];
    int wid = (blockIdx.x * 256 + threadIdx.x) >> 6;
    int nw = (gridDim.x * 256) >> 6;
    for (int node = wid; node < Nn; node += nw) {
        int s0 = starts[node], s1 = starts[node + 1];
        float4 p0 = *(const float4*)&xp[node * 8];
        float4 p1 = *(const float4*)&xp[node * 8 + 4];
        float prex = b1x + p0.x * w1x[0] + p0.y * w1x[1] + p0.z * w1x[2] + p0.w * w1x[3]
                   + p1.x * w1x[4] + p1.y * w1x[5] + p1.z * w1x[6];
        float prey = b1y + p0.x * w1y[0] + p0.y * w1y[1] + p0.z * w1y[2] + p0.w * w1y[3]
                   + p1.x * w1y[4] + p1.y * w1y[5] + p1.z * w1y[6];
        float accx = 0.0f, accy = 0.0f;
        int slot = s0;
        for (; slot + 2 <= s1; slot += 2) {
            int sA = src_s[slot], sB = src_s[slot + 1];
            float4 eA = ea_s[slot], eB = ea_s[slot + 1];
            float4 a0 = *(const float4*)&xp[sA * 8];
            float4 a1 = *(const float4*)&xp[sA * 8 + 4];
            float4 b0 = *(const float4*)&xp[sB * 8];
            float4 b1v = *(const float4*)&xp[sB * 8 + 4];
            float u0 = prex + a0.x * w1x[7] + a0.y * w1x[8] + a0.z * w1x[9] + a0.w * w1x[10]
                     + a1.x * w1x[11] + a1.y * w1x[12] + a1.z * w1x[13]
                     + eA.x * w1x[14] + eA.y * w1x[15] + eA.z * w1x[16] + eA.w * w1x[17];
            float u1 = prey + a0.x * w1y[7] + a0.y * w1y[8] + a0.z * w1y[9] + a0.w * w1y[10]
                     + a1.x * w1y[11] + a1.y * w1y[12] + a1.z * w1y[13]
                     + eA.x * w1y[14] + eA.y * w1y[15] + eA.z * w1y[16] + eA.w * w1y[17];
            float v0 = prex + b0.x * w1x[7] + b0.y * w1x[8] + b0.z * w1x[9] + b0.w * w1x[10]
                     + b1v.x * w1x[11] + b1v.y * w1x[12] + b1v.z * w1x[13]
                     + eB.x * w1x[14] + eB.y * w1x[15] + eB.z * w1x[16] + eB.w * w1x[17];
            float v1 = prey + b0.x * w1y[7] + b0.y * w1y[8] + b0.z * w1y[9] + b0.w * w1y[10]
                     + b1v.x * w1y[11] + b1v.y * w1y[12] + b1v.z * w1y[13]
                     + eB.x * w1y[14] + eB.y * w1y[15] + eB.z * w1y[16] + eB.w * w1y[17];
            accx += fmaxf(u0, 0.0f) + fmaxf(v0, 0.0f);
            accy += fmaxf(u1, 0.0f) + fmaxf(v1, 0.0f);
        }
        if (slot < s1) {
            int sA = src_s[slot];
            float4 eA = ea_s[slot];
            float4 a0 = *(const float4*)&xp[sA * 8];
            float4 a1 = *(const float4*)&xp[sA * 8 + 4];
            float u0 = prex + a0.x * w1x[7] + a0.y * w1x[8] + a0.z * w1x[9] + a0.w * w1x[10]
                     + a1.x * w1x[11] + a1.y * w1x[12] + a1.z * w1x[13]
                     + eA.x * w1x[14] + eA.y * w1x[15] + eA.z * w1x[16] + eA.w * w1x[17];
            float u1 = prey + a0.x * w1y[7] + a0.y * w1y[8] + a0.z * w1y[9] + a0.w * w1y[10]
                     + a1.x * w1y[11] + a1.y * w1y[12] + a1.z * w1y[13]
                     + eA.x * w1y[14] + eA.y * w1y[15] + eA.z * w1y[16] + eA.w * w1y[17];
            accx += fmaxf(u0, 0.0f);
            accy += fmaxf(u1, 0.0f);
        }
        tout[node * Hd + lane] = accx;
        tout[node * Hd + lane + 64] = accy;
    }
}

// MFMA multi-source GEMM, LDS-free K-loop, fragment-swizzled W (unchanged r7).
__global__ __launch_bounds__(256, 2) void tag_gemm_mfma(
    const float* __restrict__ P0,
    const unsigned short* __restrict__ Pb1, const unsigned short* __restrict__ Pb2,
    const unsigned short* __restrict__ Pb3,
    const unsigned short* __restrict__ WThi, const unsigned short* __restrict__ WTlo,
    const float* __restrict__ bias, const int* __restrict__ rowdeg,
    float* __restrict__ C, unsigned short* __restrict__ Cb16,
    int nsrc, int reluflag) {
    __shared__ float Cl[64 * 132];
    const int tid = threadIdx.x;
    const int lane = tid & 63;
    const int wv = tid >> 6;
    const int l15 = lane & 15;
    const int quad = lane >> 4;
    const int rowbase = blockIdx.x * 64;
    const int arow = min(rowbase + wv * 16 + l15, Nn - 1);

    float4v acc[8];
#pragma unroll
    for (int nt = 0; nt < 8; ++nt) acc[nt] = (float4v)0.0f;

#pragma unroll
    for (int kc = 0; kc < 4; ++kc) {
        const float* ap = &P0[(size_t)arow * Hd + kc * 32 + quad * 8];
        float4 fa = *(const float4*)ap;
        float4 fb = *(const float4*)(ap + 4);
        U4 ahi, alo;
        split2(fa.x, fa.y, ahi.u.x, alo.u.x);
        split2(fa.z, fa.w, ahi.u.y, alo.u.y);
        split2(fb.x, fb.y, ahi.u.z, alo.u.z);
        split2(fb.z, fb.w, ahi.u.w, alo.u.w);
        const unsigned short* whp = WThi + (size_t)(kc * 8) * 512 + lane * 8;
        const unsigned short* wlp = WTlo + (size_t)(kc * 8) * 512 + lane * 8;
#pragma unroll
        for (int nt = 0; nt < 8; ++nt) {
            U4 wh, wl;
            wh.u = *(const uint4*)&whp[nt * 512];
            wl.u = *(const uint4*)&wlp[nt * 512];
            acc[nt] = __builtin_amdgcn_mfma_f32_16x16x32_bf16(ahi.s, wh.s, acc[nt], 0, 0, 0);
            acc[nt] = __builtin_amdgcn_mfma_f32_16x16x32_bf16(alo.s, wh.s, acc[nt], 0, 0, 0);
            acc[nt] = __builtin_amdgcn_mfma_f32_16x16x32_bf16(ahi.s, wl.s, acc[nt], 0, 0, 0);
        }
    }
#pragma unroll 1
    for (int g = 1; g < nsrc; ++g) {
        const unsigned short* Pb = (g == 1) ? Pb1 : (g == 2) ? Pb2 : Pb3;
        const unsigned short* Whg = WThi + (size_t)g * 16384;
        const unsigned short* Wlg = WTlo + (size_t)g * 16384;
#pragma unroll
        for (int kc = 0; kc < 4; ++kc) {
            U4 ab;
            ab.u = *(const uint4*)&Pb[(size_t)arow * Hd + kc * 32 + quad * 8];
            const unsigned short* whp = Whg + (size_t)(kc * 8) * 512 + lane * 8;
            const unsigned short* wlp = Wlg + (size_t)(kc * 8) * 512 + lane * 8;
#pragma unroll
            for (int nt = 0; nt < 8; ++nt) {
                U4 wh, wl;
                wh.u = *(const uint4*)&whp[nt * 512];
                wl.u = *(const uint4*)&wlp[nt * 512];
                acc[nt] = __builtin_amdgcn_mfma_f32_16x16x32_bf16(ab.s, wh.s, acc[nt], 0, 0, 0);
                acc[nt] = __builtin_amdgcn_mfma_f32_16x16x32_bf16(ab.s, wl.s, acc[nt], 0, 0, 0);
            }
        }
    }
#pragma unroll
    for (int nt = 0; nt < 8; ++nt)
#pragma unroll
        for (int reg = 0; reg < 4; ++reg)
            Cl[(wv * 16 + quad * 4 + reg) * 132 + nt * 16 + l15] = acc[nt][reg];
    __syncthreads();
#pragma unroll
    for (int i = 0; i < 8; ++i) {
        int s = tid + i * 256;
        int r = s >> 5, c4 = (s & 31) * 4;
        int grow = rowbase + r;
        if (grow < Nn) {
            float4 v = *(const float4*)&Cl[r * 132 + c4];
            float4 bv = *(const float4*)&bias[c4];
            float bs = rowdeg ? (float)rowdeg[grow] : 1.0f;
            v.x += bs * bv.x; v.y += bs * bv.y; v.z += bs * bv.z; v.w += bs * bv.w;
            if (reluflag) {
                v.x = fmaxf(v.x, 0.0f); v.y = fmaxf(v.y, 0.0f);
                v.z = fmaxf(v.z, 0.0f); v.w = fmaxf(v.w, 0.0f);
            }
            *(float4*)&C[(size_t)grow * Hd + c4] = v;
            if (Cb16) {
                uint2 p;
                p.x = bf16rne(v.x) | (bf16rne(v.y) << 16);
                p.y = bf16rne(v.z) | (bf16rne(v.w) << 16);
                *(uint2*)&Cb16[(size_t)grow * Hd + c4] = p;
            }
        }
    }
}

// bf16 hop v4: COLUMN-BLOCKED for per-XCD L2 residency. 4 passes of 32 cols
// (64 B/row -> 3.2 MB working set < 4 MB L2/XCD). cb-major grid clusters each
// pass in dispatch order. Within a wave: 16-lane groups, 4 edges per gather
// inst (dword/lane), 2x unroll; combine via shfl_xor(16,32).
__global__ void hop_kernel(const unsigned short* __restrict__ pin,
                           unsigned short* __restrict__ pout,
                           const int* __restrict__ starts, const int* __restrict__ src_s,
                           const float* __restrict__ w_s) {
    const int NB = Nn / 4;                 // 12500 blocks per column pass
    int cb = blockIdx.x / NB;              // 0..3
    int nb = blockIdx.x - cb * NB;
    int node = nb * 4 + (threadIdx.x >> 6);
    int lane = threadIdx.x & 63;
    int q = lane >> 4, r = lane & 15;      // group q = edge slot+q; lane covers 2 cols
    const unsigned short* pcol = pin + cb * 32;
    int s0 = starts[node], s1 = starts[node + 1];
    float a0 = 0.0f, a1 = 0.0f;
    int slot = s0;
    for (; slot + 8 <= s1; slot += 8) {
        int i0 = slot + q, i1 = slot + 4 + q;
        int sA = src_s[i0], sB = src_s[i1];
        float wA = w_s[i0], wB = w_s[i1];
        unsigned vA = *(const unsigned*)&pcol[(size_t)sA * Hd + r * 2];
        unsigned vB = *(const unsigned*)&pcol[(size_t)sB * Hd + r * 2];
        a0 += wA * bf16lo(vA) + wB * bf16lo(vB);
        a1 += wA * bf16hi(vA) + wB * bf16hi(vB);
    }
    if (slot + 4 <= s1) {
        int i0 = slot + q;
        int sA = src_s[i0];
        float wA = w_s[i0];
        unsigned vA = *(const unsigned*)&pcol[(size_t)sA * Hd + r * 2];
        a0 += wA * bf16lo(vA);
        a1 += wA * bf16hi(vA);
        slot += 4;
    }
    if (slot < s1) {  // 1-3 edge masked tail
        int idx = min(slot + q, s1 - 1);
        float wA = (slot + q < s1) ? w_s[idx] : 0.0f;
        int sA = src_s[idx];
        unsigned vA = *(const unsigned*)&pcol[(size_t)sA * Hd + r * 2];
        a0 += wA * bf16lo(vA);
        a1 += wA * bf16hi(vA);
    }
    a0 += __shfl_xor(a0, 16);
    a0 += __shfl_xor(a0, 32);
    a1 += __shfl_xor(a1, 16);
    a1 += __shfl_xor(a1, 32);
    if (q == 0) {
        unsigned o = bf16rne(a0) | (bf16rne(a1) << 16);
        *(unsigned*)&pout[(size_t)node * Hd + cb * 32 + r * 2] = o;
    }
}

__global__ void out_kernel(const float* __restrict__ hin, const float* __restrict__ oW,
                           const float* __restrict__ ob, float* __restrict__ y) {
    __shared__ float w[256];
    __shared__ float bb[2];
    w[threadIdx.x] = oW[threadIdx.x & 255];
    if (threadIdx.x < 2) bb[threadIdx.x] = ob[threadIdx.x];
    __syncthreads();
    int i = blockIdx.x * blockDim.x + threadIdx.x;
    if (i < Nn) {
        float a0 = bb[0], a1 = bb[1];
#pragma unroll
        for (int k = 0; k < Hd; k += 4) {
            float4 hv = *(const float4*)&hin[i * Hd + k];
            a0 += hv.x * w[2 * k] + hv.y * w[2 * k + 2] + hv.z * w[2 * k + 4] + hv.w * w[2 * k + 6];
            a1 += hv.x * w[2 * k + 1] + hv.y * w[2 * k + 3] + hv.z * w[2 * k + 5] + hv.w * w[2 * k + 7];
        }
        *(float2*)&y[i * 2] = make_float2(a0, a1);
    }
}

extern "C" void kernel_launch(void* const* d_in, const int* in_sizes, int n_in,
                              void* d_out, int out_size, void* d_ws, size_t ws_size,
                              hipStream_t stream) {
    const float* x    = (const float*)d_in[0];
    const int*   ei   = (const int*)d_in[1];
    const float* ea   = (const float*)d_in[2];
    const float* eW1  = (const float*)d_in[3];
    const float* eb1  = (const float*)d_in[4];
    const float* eW2  = (const float*)d_in[5];
    const float* eb2  = (const float*)d_in[6];
    const float* tagW = (const float*)d_in[7];
    const float* tagb = (const float*)d_in[8];
    const float* oW   = (const float*)d_in[9];
    const float* ob   = (const float*)d_in[10];
    float* y = (float*)d_out;
    const int* row = ei;        // source
    const int* col = ei + Ee;   // target

    char* wp = (char*)d_ws;
    auto carve = [&](size_t bytes) -> char* {
        char* p = wp;
        wp += (bytes + 15) & ~(size_t)15;
        return p;
    };
    int* deg     = (int*)carve((size_t)2 * Nn * 4);
    int* cnt     = deg + Nn;
    int* starts  = (int*)carve((size_t)(Nn + 1) * 4);
    float* dinv  = (float*)carve((size_t)Nn * 4);
    int* src_s   = (int*)carve((size_t)Ee * 4);
    float* w_s   = (float*)carve((size_t)Ee * 4);
    float4* ea_s = (float4*)carve((size_t)Ee * 16);
    unsigned short* WThi = (unsigned short*)carve((size_t)17 * 16384 * 2);
    unsigned short* WTlo = (unsigned short*)carve((size_t)17 * 16384 * 2);
    float* hbuf  = (float*)carve((size_t)Nn * Hd * 4);
    float* obuf  = (float*)carve((size_t)Nn * Hd * 4);
    unsigned short* hb16 = (unsigned short*)carve((size_t)Nn * Hd * 2);
    unsigned short* pb0  = (unsigned short*)carve((size_t)Nn * Hd * 2);
    unsigned short* pb1  = (unsigned short*)carve((size_t)Nn * Hd * 2);
    unsigned short* pb2  = (unsigned short*)carve((size_t)Nn * Hd * 2);
    float* xp    = (float*)pb1;   // alias: dead until hop phase

    zero_int_kernel<<<400, 256, 0, stream>>>(deg, 2 * Nn);
    count_kernel<<<(Ee + 255) / 256, 256, 0, stream>>>(col, deg);
    wconv_kernel<<<(17 * 16384 + 255) / 256, 256, 0, stream>>>(eW2, tagW, WThi, WTlo);
    xpack_kernel<<<(Nn + 255) / 256, 256, 0, stream>>>(x, xp);
    scan_kernel<<<1, 1024, 0, stream>>>(deg, starts, dinv);
    fill_kernel<<<(Ee + 255) / 256, 256, 0, stream>>>(row, col, starts, cnt, dinv, ea,
                                                      src_s, w_s, ea_s);
    // t = per-target sum of relu(layer1)  (into obuf fp32)
    edge_l1_kernel<<<3125, 256, 0, stream>>>(xp, ea_s, starts, src_s, eW1, eb1, obuf);
    // h0 = t @ W2 + deg*b2  (fp32 into hbuf, bf16 copy into hb16)
    const int gemm_grid = (Nn + 63) / 64;
    tag_gemm_mfma<<<gemm_grid, 256, 0, stream>>>(obuf, nullptr, nullptr, nullptr,
                                                 WThi, WTlo, eb2, deg,
                                                 hbuf, hb16, 1, 0);

    const int hop_grid = 4 * (Nn / 4);  // cb-major: 4 column passes x 12500 blocks
    for (int l = 0; l < Ld; ++l) {
        hop_kernel<<<hop_grid, 256, 0, stream>>>(hb16, pb0, starts, src_s, w_s);
        hop_kernel<<<hop_grid, 256, 0, stream>>>(pb0, pb1, starts, src_s, w_s);
        hop_kernel<<<hop_grid, 256, 0, stream>>>(pb1, pb2, starts, src_s, w_s);
        tag_gemm_mfma<<<gemm_grid, 256, 0, stream>>>(
            hbuf, pb0, pb1, pb2,
            WThi + (size_t)(1 + l * 4) * 16384, WTlo + (size_t)(1 + l * 4) * 16384,
            tagb + l * Hd, nullptr, obuf,
            (l < Ld - 1) ? hb16 : nullptr, 4, (l < Ld - 1) ? 1 : 0);
        float* t = hbuf; hbuf = obuf; obuf = t;
    }
    out_kernel<<<(Nn + 255) / 256, 256, 0, stream>>>(hbuf, oW, ob, y);
}

// Round 11
// 861.606 us; speedup vs baseline: 1.5958x; 1.5958x over previous
//
#include <hip/hip_runtime.h>

#define Nn 50000
#define Ee 600000
#define Hd 128
#define Ld 4
#define Kd 3

typedef __attribute__((ext_vector_type(8))) short short8;
typedef __attribute__((ext_vector_type(4))) float float4v;

union U4 { uint4 u; short8 s; };

__device__ __forceinline__ unsigned bf16rne(float f) {
    unsigned u = __float_as_uint(f);
    return (u + 0x7fffu + ((u >> 16) & 1u)) >> 16;
}
__device__ __forceinline__ void split2(float f0, float f1, unsigned& hd, unsigned& ld) {
    unsigned h0 = bf16rne(f0), h1 = bf16rne(f1);
    float r0 = f0 - __uint_as_float(h0 << 16);
    float r1 = f1 - __uint_as_float(h1 << 16);
    unsigned l0 = bf16rne(r0), l1 = bf16rne(r1);
    hd = h0 | (h1 << 16);
    ld = l0 | (l1 << 16);
}
__device__ __forceinline__ float bf16lo(unsigned v) { return __uint_as_float(v << 16); }
__device__ __forceinline__ float bf16hi(unsigned v) { return __uint_as_float(v & 0xffff0000u); }

__global__ void zero_int_kernel(int* __restrict__ p, int n) {
    int i = blockIdx.x * blockDim.x + threadIdx.x;
    int stride = gridDim.x * blockDim.x;
    for (; i < n; i += stride) p[i] = 0;
}

__global__ void count_kernel(const int* __restrict__ col, int* __restrict__ deg) {
    int e = blockIdx.x * blockDim.x + threadIdx.x;
    if (e < Ee) atomicAdd(&deg[col[e]], 1);
}

// Shfl-based exclusive scan.
__global__ void scan_kernel(const int* __restrict__ deg, int* __restrict__ starts,
                            float* __restrict__ dinv) {
    __shared__ int wsum[16];
    __shared__ int carry_s;
    int tid = threadIdx.x;
    int lane = tid & 63, w = tid >> 6;
    if (tid == 0) carry_s = 0;
    __syncthreads();
    for (int base = 0; base < Nn; base += 1024) {
        int i = base + tid;
        int v = (i < Nn) ? deg[i] : 0;
        if (i < Nn) dinv[i] = (v > 0) ? rsqrtf((float)v) : 0.0f;
        int s = v;
#pragma unroll
        for (int off = 1; off < 64; off <<= 1) {
            int t = __shfl_up(s, off);
            if (lane >= off) s += t;
        }
        if (lane == 63) wsum[w] = s;
        __syncthreads();
        if (w == 0) {
            int ws = (lane < 16) ? wsum[lane] : 0;
#pragma unroll
            for (int off = 1; off < 16; off <<= 1) {
                int t = __shfl_up(ws, off);
                if (lane >= off) ws += t;
            }
            if (lane < 16) wsum[lane] = ws;
        }
        __syncthreads();
        int woff = (w > 0) ? wsum[w - 1] : 0;
        int carry = carry_s;
        if (i < Nn) starts[i] = carry + woff + s - v;
        __syncthreads();
        if (tid == 1023) carry_s = carry + wsum[15];
    }
    __syncthreads();
    if (threadIdx.x == 0) starts[Nn] = carry_s;
}

// CSR fill; writes ea_s (slot-ordered edge attrs) directly.
__global__ void fill_kernel(const int* __restrict__ row, const int* __restrict__ col,
                            const int* __restrict__ starts, int* __restrict__ cnt,
                            const float* __restrict__ dinv, const float* __restrict__ ea,
                            int* __restrict__ src_s, float* __restrict__ w_s,
                            float4* __restrict__ ea_s) {
    int e = blockIdx.x * blockDim.x + threadIdx.x;
    if (e < Ee) {
        int c = col[e], r = row[e];
        float4 ev = *(const float4*)&ea[(size_t)e * 4];
        int slot = starts[c] + atomicAdd(&cnt[c], 1);
        src_s[slot] = r;
        w_s[slot] = dinv[r] * dinv[c];
        ea_s[slot] = ev;
    }
}

// x [N][7] -> padded aligned xp [N][8] (pad = 0)
__global__ void xpack_kernel(const float* __restrict__ x, float* __restrict__ xp) {
    int i = blockIdx.x * blockDim.x + threadIdx.x;
    if (i < Nn) {
        float4 a = make_float4(x[i * 7], x[i * 7 + 1], x[i * 7 + 2], x[i * 7 + 3]);
        float4 b = make_float4(x[i * 7 + 4], x[i * 7 + 5], x[i * 7 + 6], 0.0f);
        *(float4*)&xp[i * 8] = a;
        *(float4*)&xp[i * 8 + 4] = b;
    }
}

// 17 weight matrices [k][n] fp32 -> FRAGMENT-SWIZZLED bf16 hi/lo planes.
__global__ void wconv_kernel(const float* __restrict__ eW2, const float* __restrict__ tagW,
                             unsigned short* __restrict__ WThi,
                             unsigned short* __restrict__ WTlo) {
    int id = blockIdx.x * blockDim.x + threadIdx.x;
    if (id >= 17 * 16384) return;
    int m = id >> 14;
    int rem = id & 16383;
    int n = rem >> 7, k = rem & 127;
    const float* src = (m == 0) ? eW2 : tagW + (size_t)(m - 1) * 16384;
    float f = src[k * Hd + n];
    unsigned h = bf16rne(f);
    float r = f - __uint_as_float(h << 16);
    int kc = k >> 5, quad = (k >> 3) & 3, j = k & 7;
    int nt = n >> 4, l15 = n & 15;
    int lane = quad * 16 + l15;
    int idx = (m << 14) + (((kc * 8 + nt) * 64) + lane) * 8 + j;
    WThi[idx] = (unsigned short)h;
    WTlo[idx] = (unsigned short)bf16rne(r);
}

// Layer-1-only edge pass (r8 form).
__global__ __launch_bounds__(256) void edge_l1_kernel(
    const float* __restrict__ xp, const float4* __restrict__ ea_s,
    const int* __restrict__ starts, const int* __restrict__ src_s,
    const float* __restrict__ eW1, const float* __restrict__ eb1,
    float* __restrict__ tout) {
    int lane = threadIdx.x & 63;
    float w1x[18], w1y[18];
#pragma unroll
    for (int j = 0; j < 18; ++j) {
        w1x[j] = eW1[j * Hd + lane];
        w1y[j] = eW1[j * Hd + lane + 64];
    }
    float b1x = eb1[lane], b1y = eb1[lane + 64];
    int wid = (blockIdx.x * 256 + threadIdx.x) >> 6;
    int nw = (gridDim.x * 256) >> 6;
    for (int node = wid; node < Nn; node += nw) {
        int s0 = starts[node], s1 = starts[node + 1];
        float4 p0 = *(const float4*)&xp[node * 8];
        float4 p1 = *(const float4*)&xp[node * 8 + 4];
        float prex = b1x + p0.x * w1x[0] + p0.y * w1x[1] + p0.z * w1x[2] + p0.w * w1x[3]
                   + p1.x * w1x[4] + p1.y * w1x[5] + p1.z * w1x[6];
        float prey = b1y + p0.x * w1y[0] + p0.y * w1y[1] + p0.z * w1y[2] + p0.w * w1y[3]
                   + p1.x * w1y[4] + p1.y * w1y[5] + p1.z * w1y[6];
        float accx = 0.0f, accy = 0.0f;
        int slot = s0;
        for (; slot + 2 <= s1; slot += 2) {
            int sA = src_s[slot], sB = src_s[slot + 1];
            float4 eA = ea_s[slot], eB = ea_s[slot + 1];
            float4 a0 = *(const float4*)&xp[sA * 8];
            float4 a1 = *(const float4*)&xp[sA * 8 + 4];
            float4 b0 = *(const float4*)&xp[sB * 8];
            float4 b1v = *(const float4*)&xp[sB * 8 + 4];
            float u0 = prex + a0.x * w1x[7] + a0.y * w1x[8] + a0.z * w1x[9] + a0.w * w1x[10]
                     + a1.x * w1x[11] + a1.y * w1x[12] + a1.z * w1x[13]
                     + eA.x * w1x[14] + eA.y * w1x[15] + eA.z * w1x[16] + eA.w * w1x[17];
            float u1 = prey + a0.x * w1y[7] + a0.y * w1y[8] + a0.z * w1y[9] + a0.w * w1y[10]
                     + a1.x * w1y[11] + a1.y * w1y[12] + a1.z * w1y[13]
                     + eA.x * w1y[14] + eA.y * w1y[15] + eA.z * w1y[16] + eA.w * w1y[17];
            float v0 = prex + b0.x * w1x[7] + b0.y * w1x[8] + b0.z * w1x[9] + b0.w * w1x[10]
                     + b1v.x * w1x[11] + b1v.y * w1x[12] + b1v.z * w1x[13]
                     + eB.x * w1x[14] + eB.y * w1x[15] + eB.z * w1x[16] + eB.w * w1x[17];
            float v1 = prey + b0.x * w1y[7] + b0.y * w1y[8] + b0.z * w1y[9] + b0.w * w1y[10]
                     + b1v.x * w1y[11] + b1v.y * w1y[12] + b1v.z * w1y[13]
                     + eB.x * w1y[14] + eB.y * w1y[15] + eB.z * w1y[16] + eB.w * w1y[17];
            accx += fmaxf(u0, 0.0f) + fmaxf(v0, 0.0f);
            accy += fmaxf(u1, 0.0f) + fmaxf(v1, 0.0f);
        }
        if (slot < s1) {
            int sA = src_s[slot];
            float4 eA = ea_s[slot];
            float4 a0 = *(const float4*)&xp[sA * 8];
            float4 a1 = *(const float4*)&xp[sA * 8 + 4];
            float u0 = prex + a0.x * w1x[7] + a0.y * w1x[8] + a0.z * w1x[9] + a0.w * w1x[10]
                     + a1.x * w1x[11] + a1.y * w1x[12] + a1.z * w1x[13]
                     + eA.x * w1x[14] + eA.y * w1x[15] + eA.z * w1x[16] + eA.w * w1x[17];
            float u1 = prey + a0.x * w1y[7] + a0.y * w1y[8] + a0.z * w1y[9] + a0.w * w1y[10]
                     + a1.x * w1y[11] + a1.y * w1y[12] + a1.z * w1y[13]
                     + eA.x * w1y[14] + eA.y * w1y[15] + eA.z * w1y[16] + eA.w * w1y[17];
            accx += fmaxf(u0, 0.0f);
            accy += fmaxf(u1, 0.0f);
        }
        tout[node * Hd + lane] = accx;
        tout[node * Hd + lane + 64] = accy;
    }
}

// MFMA multi-source GEMM, LDS-free K-loop, fragment-swizzled W. When yout is
// non-null (final layer), the output head y = C @ oW + ob is fused into the
// epilogue (C kept in LDS, stride 133 = conflict-free) and C is NOT stored.
__global__ __launch_bounds__(256, 2) void tag_gemm_mfma(
    const float* __restrict__ P0,
    const unsigned short* __restrict__ Pb1, const unsigned short* __restrict__ Pb2,
    const unsigned short* __restrict__ Pb3,
    const unsigned short* __restrict__ WThi, const unsigned short* __restrict__ WTlo,
    const float* __restrict__ bias, const int* __restrict__ rowdeg,
    float* __restrict__ C, unsigned short* __restrict__ Cb16,
    const float* __restrict__ oW, const float* __restrict__ ob,
    float* __restrict__ yout, int nsrc, int reluflag) {
    __shared__ float Cl[64 * 133];  // stride 133: conflict-free b128 row reads
    __shared__ float oWs[256];
    __shared__ float obs[2];
    const int tid = threadIdx.x;
    const int lane = tid & 63;
    const int wv = tid >> 6;
    const int l15 = lane & 15;
    const int quad = lane >> 4;
    const int rowbase = blockIdx.x * 64;
    const int arow = min(rowbase + wv * 16 + l15, Nn - 1);
    if (yout) {
        oWs[tid] = oW[tid & 255];
        if (tid < 2) obs[tid] = ob[tid];
    }

    float4v acc[8];
#pragma unroll
    for (int nt = 0; nt < 8; ++nt) acc[nt] = (float4v)0.0f;

#pragma unroll
    for (int kc = 0; kc < 4; ++kc) {
        const float* ap = &P0[(size_t)arow * Hd + kc * 32 + quad * 8];
        float4 fa = *(const float4*)ap;
        float4 fb = *(const float4*)(ap + 4);
        U4 ahi, alo;
        split2(fa.x, fa.y, ahi.u.x, alo.u.x);
        split2(fa.z, fa.w, ahi.u.y, alo.u.y);
        split2(fb.x, fb.y, ahi.u.z, alo.u.z);
        split2(fb.z, fb.w, ahi.u.w, alo.u.w);
        const unsigned short* whp = WThi + (size_t)(kc * 8) * 512 + lane * 8;
        const unsigned short* wlp = WTlo + (size_t)(kc * 8) * 512 + lane * 8;
#pragma unroll
        for (int nt = 0; nt < 8; ++nt) {
            U4 wh, wl;
            wh.u = *(const uint4*)&whp[nt * 512];
            wl.u = *(const uint4*)&wlp[nt * 512];
            acc[nt] = __builtin_amdgcn_mfma_f32_16x16x32_bf16(ahi.s, wh.s, acc[nt], 0, 0, 0);
            acc[nt] = __builtin_amdgcn_mfma_f32_16x16x32_bf16(alo.s, wh.s, acc[nt], 0, 0, 0);
            acc[nt] = __builtin_amdgcn_mfma_f32_16x16x32_bf16(ahi.s, wl.s, acc[nt], 0, 0, 0);
        }
    }
#pragma unroll 1
    for (int g = 1; g < nsrc; ++g) {
        const unsigned short* Pb = (g == 1) ? Pb1 : (g == 2) ? Pb2 : Pb3;
        const unsigned short* Whg = WThi + (size_t)g * 16384;
        const unsigned short* Wlg = WTlo + (size_t)g * 16384;
#pragma unroll
        for (int kc = 0; kc < 4; ++kc) {
            U4 ab;
            ab.u = *(const uint4*)&Pb[(size_t)arow * Hd + kc * 32 + quad * 8];
            const unsigned short* whp = Whg + (size_t)(kc * 8) * 512 + lane * 8;
            const unsigned short* wlp = Wlg + (size_t)(kc * 8) * 512 + lane * 8;
#pragma unroll
            for (int nt = 0; nt < 8; ++nt) {
                U4 wh, wl;
                wh.u = *(const uint4*)&whp[nt * 512];
                wl.u = *(const uint4*)&wlp[nt * 512];
                acc[nt] = __builtin_amdgcn_mfma_f32_16x16x32_bf16(ab.s, wh.s, acc[nt], 0, 0, 0);
                acc[nt] = __builtin_amdgcn_mfma_f32_16x16x32_bf16(ab.s, wl.s, acc[nt], 0, 0, 0);
            }
        }
    }
#pragma unroll
    for (int nt = 0; nt < 8; ++nt)
#pragma unroll
        for (int reg = 0; reg < 4; ++reg)
            Cl[(wv * 16 + quad * 4 + reg) * 133 + nt * 16 + l15] = acc[nt][reg];
    __syncthreads();
#pragma unroll
    for (int i = 0; i < 8; ++i) {
        int s = tid + i * 256;
        int r = s >> 5, c4 = (s & 31) * 4;
        int grow = rowbase + r;
        if (grow < Nn) {
            float4 v = *(const float4*)&Cl[r * 133 + c4];
            float4 bv = *(const float4*)&bias[c4];
            float bs = rowdeg ? (float)rowdeg[grow] : 1.0f;
            v.x += bs * bv.x; v.y += bs * bv.y; v.z += bs * bv.z; v.w += bs * bv.w;
            if (reluflag) {
                v.x = fmaxf(v.x, 0.0f); v.y = fmaxf(v.y, 0.0f);
                v.z = fmaxf(v.z, 0.0f); v.w = fmaxf(v.w, 0.0f);
            }
            if (yout) {
                *(float4*)&Cl[r * 133 + c4] = v;  // keep in LDS for the head
            } else {
                *(float4*)&C[(size_t)grow * Hd + c4] = v;
                if (Cb16) {
                    uint2 p;
                    p.x = bf16rne(v.x) | (bf16rne(v.y) << 16);
                    p.y = bf16rne(v.z) | (bf16rne(v.w) << 16);
                    *(uint2*)&Cb16[(size_t)grow * Hd + c4] = p;
                }
            }
        }
    }
    if (yout) {
        __syncthreads();
        if (tid < 64) {
            int grow = rowbase + tid;
            if (grow < Nn) {
                float a0 = obs[0], a1 = obs[1];
#pragma unroll
                for (int c = 0; c < Hd; c += 4) {
                    float4 t = *(const float4*)&Cl[tid * 133 + c];
                    a0 += t.x * oWs[2 * c] + t.y * oWs[2 * c + 2]
                        + t.z * oWs[2 * c + 4] + t.w * oWs[2 * c + 6];
                    a1 += t.x * oWs[2 * c + 1] + t.y * oWs[2 * c + 3]
                        + t.z * oWs[2 * c + 5] + t.w * oWs[2 * c + 7];
                }
                *(float2*)&yout[(size_t)grow * 2] = make_float2(a0, a1);
            }
        }
    }
}

// bf16 hop v5: quarter-wave split, single UNIFORM stride-4 loop (no tail
// duplication/masking — r10 showed per-visit loop cost dominates, so minimize
// iterations and control flow). 16 lanes x 16 B cover one 256-B row; one
// dwordx4 gather serves 4 edges. Combine via shfl_xor(16,32).
__global__ void hop_kernel(const unsigned short* __restrict__ pin,
                           unsigned short* __restrict__ pout,
                           const int* __restrict__ starts, const int* __restrict__ src_s,
                           const float* __restrict__ w_s) {
    int lane = threadIdx.x & 63;
    int q = lane >> 4, r = lane & 15;
    int node = (blockIdx.x * blockDim.x + threadIdx.x) >> 6;
    if (node >= Nn) return;
    int s0 = starts[node], s1 = starts[node + 1];
    float a[8];
#pragma unroll
    for (int i = 0; i < 8; ++i) a[i] = 0.0f;
    for (int slot = s0 + q; slot < s1; slot += 4) {
        int src = src_s[slot];
        float w = w_s[slot];
        uint4 v = *(const uint4*)&pin[(size_t)src * Hd + r * 8];
        a[0] += w * bf16lo(v.x); a[1] += w * bf16hi(v.x);
        a[2] += w * bf16lo(v.y); a[3] += w * bf16hi(v.y);
        a[4] += w * bf16lo(v.z); a[5] += w * bf16hi(v.z);
        a[6] += w * bf16lo(v.w); a[7] += w * bf16hi(v.w);
    }
#pragma unroll
    for (int i = 0; i < 8; ++i) {
        a[i] += __shfl_xor(a[i], 16);
        a[i] += __shfl_xor(a[i], 32);
    }
    if (q == 0) {
        uint4 o;
        o.x = bf16rne(a[0]) | (bf16rne(a[1]) << 16);
        o.y = bf16rne(a[2]) | (bf16rne(a[3]) << 16);
        o.z = bf16rne(a[4]) | (bf16rne(a[5]) << 16);
        o.w = bf16rne(a[6]) | (bf16rne(a[7]) << 16);
        *(uint4*)&pout[(size_t)node * Hd + r * 8] = o;
    }
}

extern "C" void kernel_launch(void* const* d_in, const int* in_sizes, int n_in,
                              void* d_out, int out_size, void* d_ws, size_t ws_size,
                              hipStream_t stream) {
    const float* x    = (const float*)d_in[0];
    const int*   ei   = (const int*)d_in[1];
    const float* ea   = (const float*)d_in[2];
    const float* eW1  = (const float*)d_in[3];
    const float* eb1  = (const float*)d_in[4];
    const float* eW2  = (const float*)d_in[5];
    const float* eb2  = (const float*)d_in[6];
    const float* tagW = (const float*)d_in[7];
    const float* tagb = (const float*)d_in[8];
    const float* oW   = (const float*)d_in[9];
    const float* ob   = (const float*)d_in[10];
    float* y = (float*)d_out;
    const int* row = ei;        // source
    const int* col = ei + Ee;   // target

    char* wp = (char*)d_ws;
    auto carve = [&](size_t bytes) -> char* {
        char* p = wp;
        wp += (bytes + 15) & ~(size_t)15;
        return p;
    };
    int* deg     = (int*)carve((size_t)2 * Nn * 4);
    int* cnt     = deg + Nn;
    int* starts  = (int*)carve((size_t)(Nn + 1) * 4);
    float* dinv  = (float*)carve((size_t)Nn * 4);
    int* src_s   = (int*)carve((size_t)Ee * 4);
    float* w_s   = (float*)carve((size_t)Ee * 4);
    float4* ea_s = (float4*)carve((size_t)Ee * 16);
    unsigned short* WThi = (unsigned short*)carve((size_t)17 * 16384 * 2);
    unsigned short* WTlo = (unsigned short*)carve((size_t)17 * 16384 * 2);
    float* hbuf  = (float*)carve((size_t)Nn * Hd * 4);
    float* obuf  = (float*)carve((size_t)Nn * Hd * 4);
    unsigned short* hb16 = (unsigned short*)carve((size_t)Nn * Hd * 2);
    unsigned short* pb0  = (unsigned short*)carve((size_t)Nn * Hd * 2);
    unsigned short* pb1  = (unsigned short*)carve((size_t)Nn * Hd * 2);
    unsigned short* pb2  = (unsigned short*)carve((size_t)Nn * Hd * 2);
    float* xp    = (float*)pb1;   // alias: dead until hop phase

    zero_int_kernel<<<400, 256, 0, stream>>>(deg, 2 * Nn);
    count_kernel<<<(Ee + 255) / 256, 256, 0, stream>>>(col, deg);
    wconv_kernel<<<(17 * 16384 + 255) / 256, 256, 0, stream>>>(eW2, tagW, WThi, WTlo);
    xpack_kernel<<<(Nn + 255) / 256, 256, 0, stream>>>(x, xp);
    scan_kernel<<<1, 1024, 0, stream>>>(deg, starts, dinv);
    fill_kernel<<<(Ee + 255) / 256, 256, 0, stream>>>(row, col, starts, cnt, dinv, ea,
                                                      src_s, w_s, ea_s);
    // t = per-target sum of relu(layer1)  (into obuf fp32)
    edge_l1_kernel<<<3125, 256, 0, stream>>>(xp, ea_s, starts, src_s, eW1, eb1, obuf);
    // h0 = t @ W2 + deg*b2  (fp32 into hbuf, bf16 copy into hb16)
    const int gemm_grid = (Nn + 63) / 64;
    tag_gemm_mfma<<<gemm_grid, 256, 0, stream>>>(obuf, nullptr, nullptr, nullptr,
                                                 WThi, WTlo, eb2, deg,
                                                 hbuf, hb16, nullptr, nullptr, nullptr,
                                                 1, 0);

    for (int l = 0; l < Ld; ++l) {
        hop_kernel<<<12500, 256, 0, stream>>>(hb16, pb0, starts, src_s, w_s);
        hop_kernel<<<12500, 256, 0, stream>>>(pb0, pb1, starts, src_s, w_s);
        hop_kernel<<<12500, 256, 0, stream>>>(pb1, pb2, starts, src_s, w_s);
        int last = (l == Ld - 1);
        tag_gemm_mfma<<<gemm_grid, 256, 0, stream>>>(
            hbuf, pb0, pb1, pb2,
            WThi + (size_t)(1 + l * 4) * 16384, WTlo + (size_t)(1 + l * 4) * 16384,
            tagb + l * Hd, nullptr, obuf,
            last ? nullptr : hb16,
            last ? oW : nullptr, last ? ob : nullptr, last ? y : nullptr,
            4, last ? 0 : 1);
        float* t = hbuf; hbuf = obuf; obuf = t;
    }
}

// Round 12
// 854.353 us; speedup vs baseline: 1.6094x; 1.0085x over previous
//
#include <hip/hip_runtime.h>

#define Nn 50000
#define Ee 600000
#define Hd 128
#define Ld 4
#define Kd 3

typedef __attribute__((ext_vector_type(8))) short short8;
typedef __attribute__((ext_vector_type(4))) float float4v;

union U4 { uint4 u; short8 s; };

__device__ __forceinline__ unsigned bf16rne(float f) {
    unsigned u = __float_as_uint(f);
    return (u + 0x7fffu + ((u >> 16) & 1u)) >> 16;
}
__device__ __forceinline__ void split2(float f0, float f1, unsigned& hd, unsigned& ld) {
    unsigned h0 = bf16rne(f0), h1 = bf16rne(f1);
    float r0 = f0 - __uint_as_float(h0 << 16);
    float r1 = f1 - __uint_as_float(h1 << 16);
    unsigned l0 = bf16rne(r0), l1 = bf16rne(r1);
    hd = h0 | (h1 << 16);
    ld = l0 | (l1 << 16);
}
__device__ __forceinline__ float bf16lo(unsigned v) { return __uint_as_float(v << 16); }
__device__ __forceinline__ float bf16hi(unsigned v) { return __uint_as_float(v & 0xffff0000u); }

__global__ void zero_int_kernel(int* __restrict__ p, int n) {
    int i = blockIdx.x * blockDim.x + threadIdx.x;
    int stride = gridDim.x * blockDim.x;
    for (; i < n; i += stride) p[i] = 0;
}

__global__ void count_kernel(const int* __restrict__ col, int* __restrict__ deg) {
    int e = blockIdx.x * blockDim.x + threadIdx.x;
    if (e < Ee) atomicAdd(&deg[col[e]], 1);
}

// Shfl-based exclusive scan.
__global__ void scan_kernel(const int* __restrict__ deg, int* __restrict__ starts,
                            float* __restrict__ dinv) {
    __shared__ int wsum[16];
    __shared__ int carry_s;
    int tid = threadIdx.x;
    int lane = tid & 63, w = tid >> 6;
    if (tid == 0) carry_s = 0;
    __syncthreads();
    for (int base = 0; base < Nn; base += 1024) {
        int i = base + tid;
        int v = (i < Nn) ? deg[i] : 0;
        if (i < Nn) dinv[i] = (v > 0) ? rsqrtf((float)v) : 0.0f;
        int s = v;
#pragma unroll
        for (int off = 1; off < 64; off <<= 1) {
            int t = __shfl_up(s, off);
            if (lane >= off) s += t;
        }
        if (lane == 63) wsum[w] = s;
        __syncthreads();
        if (w == 0) {
            int ws = (lane < 16) ? wsum[lane] : 0;
#pragma unroll
            for (int off = 1; off < 16; off <<= 1) {
                int t = __shfl_up(ws, off);
                if (lane >= off) ws += t;
            }
            if (lane < 16) wsum[lane] = ws;
        }
        __syncthreads();
        int woff = (w > 0) ? wsum[w - 1] : 0;
        int carry = carry_s;
        if (i < Nn) starts[i] = carry + woff + s - v;
        __syncthreads();
        if (tid == 1023) carry_s = carry + wsum[15];
    }
    __syncthreads();
    if (threadIdx.x == 0) starts[Nn] = carry_s;
}

// CSR fill; writes ea_s (slot-ordered edge attrs) directly.
__global__ void fill_kernel(const int* __restrict__ row, const int* __restrict__ col,
                            const int* __restrict__ starts, int* __restrict__ cnt,
                            const float* __restrict__ dinv, const float* __restrict__ ea,
                            int* __restrict__ src_s, float* __restrict__ w_s,
                            float4* __restrict__ ea_s) {
    int e = blockIdx.x * blockDim.x + threadIdx.x;
    if (e < Ee) {
        int c = col[e], r = row[e];
        float4 ev = *(const float4*)&ea[(size_t)e * 4];
        int slot = starts[c] + atomicAdd(&cnt[c], 1);
        src_s[slot] = r;
        w_s[slot] = dinv[r] * dinv[c];
        ea_s[slot] = ev;
    }
}

// x [N][7] -> padded aligned xp [N][8] (pad = 0)
__global__ void xpack_kernel(const float* __restrict__ x, float* __restrict__ xp) {
    int i = blockIdx.x * blockDim.x + threadIdx.x;
    if (i < Nn) {
        float4 a = make_float4(x[i * 7], x[i * 7 + 1], x[i * 7 + 2], x[i * 7 + 3]);
        float4 b = make_float4(x[i * 7 + 4], x[i * 7 + 5], x[i * 7 + 6], 0.0f);
        *(float4*)&xp[i * 8] = a;
        *(float4*)&xp[i * 8 + 4] = b;
    }
}

// Decoupled gather: xjs[slot] = xp[src_s[slot]] (32 B rows, slot-ordered out).
// Pure copy -> no dependent compute, pipelines to the gather service ceiling.
// 2 lanes per slot, one float4 each.
__global__ void xgather_kernel(const int* __restrict__ src_s, const float* __restrict__ xp,
                               float* __restrict__ xjs) {
    int gid = blockIdx.x * blockDim.x + threadIdx.x;
    int slot = gid >> 1, part = gid & 1;
    if (slot < Ee) {
        int src = src_s[slot];
        float4 v = *(const float4*)&xp[(size_t)src * 8 + part * 4];
        *(float4*)&xjs[(size_t)slot * 8 + part * 4] = v;
    }
}

// 17 weight matrices [k][n] fp32 -> FRAGMENT-SWIZZLED bf16 hi/lo planes.
__global__ void wconv_kernel(const float* __restrict__ eW2, const float* __restrict__ tagW,
                             unsigned short* __restrict__ WThi,
                             unsigned short* __restrict__ WTlo) {
    int id = blockIdx.x * blockDim.x + threadIdx.x;
    if (id >= 17 * 16384) return;
    int m = id >> 14;
    int rem = id & 16383;
    int n = rem >> 7, k = rem & 127;
    const float* src = (m == 0) ? eW2 : tagW + (size_t)(m - 1) * 16384;
    float f = src[k * Hd + n];
    unsigned h = bf16rne(f);
    float r = f - __uint_as_float(h << 16);
    int kc = k >> 5, quad = (k >> 3) & 3, j = k & 7;
    int nt = n >> 4, l15 = n & 15;
    int lane = quad * 16 + l15;
    int idx = (m << 14) + (((kc * 8 + nt) * 64) + lane) * 8 + j;
    WThi[idx] = (unsigned short)h;
    WTlo[idx] = (unsigned short)bf16rne(r);
}

// Layer-1-only edge pass v3: PURE STREAMING (xjs + ea_s are slot-ordered, all
// load addresses linear in slot -> no loaded-index dependence to stall on).
__global__ __launch_bounds__(256) void edge_l1_kernel(
    const float* __restrict__ xp, const float* __restrict__ xjs,
    const float4* __restrict__ ea_s,
    const int* __restrict__ starts,
    const float* __restrict__ eW1, const float* __restrict__ eb1,
    float* __restrict__ tout) {
    int lane = threadIdx.x & 63;
    float w1x[18], w1y[18];
#pragma unroll
    for (int j = 0; j < 18; ++j) {
        w1x[j] = eW1[j * Hd + lane];
        w1y[j] = eW1[j * Hd + lane + 64];
    }
    float b1x = eb1[lane], b1y = eb1[lane + 64];
    int wid = (blockIdx.x * 256 + threadIdx.x) >> 6;
    int nw = (gridDim.x * 256) >> 6;
    for (int node = wid; node < Nn; node += nw) {
        int s0 = starts[node], s1 = starts[node + 1];
        float4 p0 = *(const float4*)&xp[node * 8];
        float4 p1 = *(const float4*)&xp[node * 8 + 4];
        float prex = b1x + p0.x * w1x[0] + p0.y * w1x[1] + p0.z * w1x[2] + p0.w * w1x[3]
                   + p1.x * w1x[4] + p1.y * w1x[5] + p1.z * w1x[6];
        float prey = b1y + p0.x * w1y[0] + p0.y * w1y[1] + p0.z * w1y[2] + p0.w * w1y[3]
                   + p1.x * w1y[4] + p1.y * w1y[5] + p1.z * w1y[6];
        float accx = 0.0f, accy = 0.0f;
        int slot = s0;
        for (; slot + 2 <= s1; slot += 2) {
            float4 a0 = *(const float4*)&xjs[(size_t)slot * 8];
            float4 a1 = *(const float4*)&xjs[(size_t)slot * 8 + 4];
            float4 b0 = *(const float4*)&xjs[(size_t)(slot + 1) * 8];
            float4 b1v = *(const float4*)&xjs[(size_t)(slot + 1) * 8 + 4];
            float4 eA = ea_s[slot], eB = ea_s[slot + 1];
            float u0 = prex + a0.x * w1x[7] + a0.y * w1x[8] + a0.z * w1x[9] + a0.w * w1x[10]
                     + a1.x * w1x[11] + a1.y * w1x[12] + a1.z * w1x[13]
                     + eA.x * w1x[14] + eA.y * w1x[15] + eA.z * w1x[16] + eA.w * w1x[17];
            float u1 = prey + a0.x * w1y[7] + a0.y * w1y[8] + a0.z * w1y[9] + a0.w * w1y[10]
                     + a1.x * w1y[11] + a1.y * w1y[12] + a1.z * w1y[13]
                     + eA.x * w1y[14] + eA.y * w1y[15] + eA.z * w1y[16] + eA.w * w1y[17];
            float v0 = prex + b0.x * w1x[7] + b0.y * w1x[8] + b0.z * w1x[9] + b0.w * w1x[10]
                     + b1v.x * w1x[11] + b1v.y * w1x[12] + b1v.z * w1x[13]
                     + eB.x * w1x[14] + eB.y * w1x[15] + eB.z * w1x[16] + eB.w * w1x[17];
            float v1 = prey + b0.x * w1y[7] + b0.y * w1y[8] + b0.z * w1y[9] + b0.w * w1y[10]
                     + b1v.x * w1y[11] + b1v.y * w1y[12] + b1v.z * w1y[13]
                     + eB.x * w1y[14] + eB.y * w1y[15] + eB.z * w1y[16] + eB.w * w1y[17];
            accx += fmaxf(u0, 0.0f) + fmaxf(v0, 0.0f);
            accy += fmaxf(u1, 0.0f) + fmaxf(v1, 0.0f);
        }
        if (slot < s1) {
            float4 a0 = *(const float4*)&xjs[(size_t)slot * 8];
            float4 a1 = *(const float4*)&xjs[(size_t)slot * 8 + 4];
            float4 eA = ea_s[slot];
            float u0 = prex + a0.x * w1x[7] + a0.y * w1x[8] + a0.z * w1x[9] + a0.w * w1x[10]
                     + a1.x * w1x[11] + a1.y * w1x[12] + a1.z * w1x[13]
                     + eA.x * w1x[14] + eA.y * w1x[15] + eA.z * w1x[16] + eA.w * w1x[17];
            float u1 = prey + a0.x * w1y[7] + a0.y * w1y[8] + a0.z * w1y[9] + a0.w * w1y[10]
                     + a1.x * w1y[11] + a1.y * w1y[12] + a1.z * w1y[13]
                     + eA.x * w1y[14] + eA.y * w1y[15] + eA.z * w1y[16] + eA.w * w1y[17];
            accx += fmaxf(u0, 0.0f);
            accy += fmaxf(u1, 0.0f);
        }
        tout[node * Hd + lane] = accx;
        tout[node * Hd + lane + 64] = accy;
    }
}

// MFMA multi-source GEMM, LDS-free K-loop, fragment-swizzled W. When yout is
// non-null (final layer), the output head y = C @ oW + ob is fused into the
// epilogue (C kept in LDS) and C is NOT stored.
__global__ __launch_bounds__(256, 2) void tag_gemm_mfma(
    const float* __restrict__ P0,
    const unsigned short* __restrict__ Pb1, const unsigned short* __restrict__ Pb2,
    const unsigned short* __restrict__ Pb3,
    const unsigned short* __restrict__ WThi, const unsigned short* __restrict__ WTlo,
    const float* __restrict__ bias, const int* __restrict__ rowdeg,
    float* __restrict__ C, unsigned short* __restrict__ Cb16,
    const float* __restrict__ oW, const float* __restrict__ ob,
    float* __restrict__ yout, int nsrc, int reluflag) {
    __shared__ float Cl[64 * 133];
    __shared__ float oWs[256];
    __shared__ float obs[2];
    const int tid = threadIdx.x;
    const int lane = tid & 63;
    const int wv = tid >> 6;
    const int l15 = lane & 15;
    const int quad = lane >> 4;
    const int rowbase = blockIdx.x * 64;
    const int arow = min(rowbase + wv * 16 + l15, Nn - 1);
    if (yout) {
        oWs[tid] = oW[tid & 255];
        if (tid < 2) obs[tid] = ob[tid];
    }

    float4v acc[8];
#pragma unroll
    for (int nt = 0; nt < 8; ++nt) acc[nt] = (float4v)0.0f;

#pragma unroll
    for (int kc = 0; kc < 4; ++kc) {
        const float* ap = &P0[(size_t)arow * Hd + kc * 32 + quad * 8];
        float4 fa = *(const float4*)ap;
        float4 fb = *(const float4*)(ap + 4);
        U4 ahi, alo;
        split2(fa.x, fa.y, ahi.u.x, alo.u.x);
        split2(fa.z, fa.w, ahi.u.y, alo.u.y);
        split2(fb.x, fb.y, ahi.u.z, alo.u.z);
        split2(fb.z, fb.w, ahi.u.w, alo.u.w);
        const unsigned short* whp = WThi + (size_t)(kc * 8) * 512 + lane * 8;
        const unsigned short* wlp = WTlo + (size_t)(kc * 8) * 512 + lane * 8;
#pragma unroll
        for (int nt = 0; nt < 8; ++nt) {
            U4 wh, wl;
            wh.u = *(const uint4*)&whp[nt * 512];
            wl.u = *(const uint4*)&wlp[nt * 512];
            acc[nt] = __builtin_amdgcn_mfma_f32_16x16x32_bf16(ahi.s, wh.s, acc[nt], 0, 0, 0);
            acc[nt] = __builtin_amdgcn_mfma_f32_16x16x32_bf16(alo.s, wh.s, acc[nt], 0, 0, 0);
            acc[nt] = __builtin_amdgcn_mfma_f32_16x16x32_bf16(ahi.s, wl.s, acc[nt], 0, 0, 0);
        }
    }
#pragma unroll 1
    for (int g = 1; g < nsrc; ++g) {
        const unsigned short* Pb = (g == 1) ? Pb1 : (g == 2) ? Pb2 : Pb3;
        const unsigned short* Whg = WThi + (size_t)g * 16384;
        const unsigned short* Wlg = WTlo + (size_t)g * 16384;
#pragma unroll
        for (int kc = 0; kc < 4; ++kc) {
            U4 ab;
            ab.u = *(const uint4*)&Pb[(size_t)arow * Hd + kc * 32 + quad * 8];
            const unsigned short* whp = Whg + (size_t)(kc * 8) * 512 + lane * 8;
            const unsigned short* wlp = Wlg + (size_t)(kc * 8) * 512 + lane * 8;
#pragma unroll
            for (int nt = 0; nt < 8; ++nt) {
                U4 wh, wl;
                wh.u = *(const uint4*)&whp[nt * 512];
                wl.u = *(const uint4*)&wlp[nt * 512];
                acc[nt] = __builtin_amdgcn_mfma_f32_16x16x32_bf16(ab.s, wh.s, acc[nt], 0, 0, 0);
                acc[nt] = __builtin_amdgcn_mfma_f32_16x16x32_bf16(ab.s, wl.s, acc[nt], 0, 0, 0);
            }
        }
    }
#pragma unroll
    for (int nt = 0; nt < 8; ++nt)
#pragma unroll
        for (int reg = 0; reg < 4; ++reg)
            Cl[(wv * 16 + quad * 4 + reg) * 133 + nt * 16 + l15] = acc[nt][reg];
    __syncthreads();
#pragma unroll
    for (int i = 0; i < 8; ++i) {
        int s = tid + i * 256;
        int r = s >> 5, c4 = (s & 31) * 4;
        int grow = rowbase + r;
        if (grow < Nn) {
            float4 v = *(const float4*)&Cl[r * 133 + c4];
            float4 bv = *(const float4*)&bias[c4];
            float bs = rowdeg ? (float)rowdeg[grow] : 1.0f;
            v.x += bs * bv.x; v.y += bs * bv.y; v.z += bs * bv.z; v.w += bs * bv.w;
            if (reluflag) {
                v.x = fmaxf(v.x, 0.0f); v.y = fmaxf(v.y, 0.0f);
                v.z = fmaxf(v.z, 0.0f); v.w = fmaxf(v.w, 0.0f);
            }
            if (yout) {
                *(float4*)&Cl[r * 133 + c4] = v;
            } else {
                *(float4*)&C[(size_t)grow * Hd + c4] = v;
                if (Cb16) {
                    uint2 p;
                    p.x = bf16rne(v.x) | (bf16rne(v.y) << 16);
                    p.y = bf16rne(v.z) | (bf16rne(v.w) << 16);
                    *(uint2*)&Cb16[(size_t)grow * Hd + c4] = p;
                }
            }
        }
    }
    if (yout) {
        __syncthreads();
        if (tid < 64) {
            int grow = rowbase + tid;
            if (grow < Nn) {
                float a0 = obs[0], a1 = obs[1];
#pragma unroll
                for (int c = 0; c < Hd; c += 4) {
                    float4 t = *(const float4*)&Cl[tid * 133 + c];
                    a0 += t.x * oWs[2 * c] + t.y * oWs[2 * c + 2]
                        + t.z * oWs[2 * c + 4] + t.w * oWs[2 * c + 6];
                    a1 += t.x * oWs[2 * c + 1] + t.y * oWs[2 * c + 3]
                        + t.z * oWs[2 * c + 5] + t.w * oWs[2 * c + 7];
                }
                *(float2*)&yout[(size_t)grow * 2] = make_float2(a0, a1);
            }
        }
    }
}

// bf16 hop v5: quarter-wave split, single uniform stride-4 loop.
__global__ void hop_kernel(const unsigned short* __restrict__ pin,
                           unsigned short* __restrict__ pout,
                           const int* __restrict__ starts, const int* __restrict__ src_s,
                           const float* __restrict__ w_s) {
    int lane = threadIdx.x & 63;
    int q = lane >> 4, r = lane & 15;
    int node = (blockIdx.x * blockDim.x + threadIdx.x) >> 6;
    if (node >= Nn) return;
    int s0 = starts[node], s1 = starts[node + 1];
    float a[8];
#pragma unroll
    for (int i = 0; i < 8; ++i) a[i] = 0.0f;
    for (int slot = s0 + q; slot < s1; slot += 4) {
        int src = src_s[slot];
        float w = w_s[slot];
        uint4 v = *(const uint4*)&pin[(size_t)src * Hd + r * 8];
        a[0] += w * bf16lo(v.x); a[1] += w * bf16hi(v.x);
        a[2] += w * bf16lo(v.y); a[3] += w * bf16hi(v.y);
        a[4] += w * bf16lo(v.z); a[5] += w * bf16hi(v.z);
        a[6] += w * bf16lo(v.w); a[7] += w * bf16hi(v.w);
    }
#pragma unroll
    for (int i = 0; i < 8; ++i) {
        a[i] += __shfl_xor(a[i], 16);
        a[i] += __shfl_xor(a[i], 32);
    }
    if (q == 0) {
        uint4 o;
        o.x = bf16rne(a[0]) | (bf16rne(a[1]) << 16);
        o.y = bf16rne(a[2]) | (bf16rne(a[3]) << 16);
        o.z = bf16rne(a[4]) | (bf16rne(a[5]) << 16);
        o.w = bf16rne(a[6]) | (bf16rne(a[7]) << 16);
        *(uint4*)&pout[(size_t)node * Hd + r * 8] = o;
    }
}

extern "C" void kernel_launch(void* const* d_in, const int* in_sizes, int n_in,
                              void* d_out, int out_size, void* d_ws, size_t ws_size,
                              hipStream_t stream) {
    const float* x    = (const float*)d_in[0];
    const int*   ei   = (const int*)d_in[1];
    const float* ea   = (const float*)d_in[2];
    const float* eW1  = (const float*)d_in[3];
    const float* eb1  = (const float*)d_in[4];
    const float* eW2  = (const float*)d_in[5];
    const float* eb2  = (const float*)d_in[6];
    const float* tagW = (const float*)d_in[7];
    const float* tagb = (const float*)d_in[8];
    const float* oW   = (const float*)d_in[9];
    const float* ob   = (const float*)d_in[10];
    float* y = (float*)d_out;
    const int* row = ei;        // source
    const int* col = ei + Ee;   // target

    char* wp = (char*)d_ws;
    auto carve = [&](size_t bytes) -> char* {
        char* p = wp;
        wp += (bytes + 15) & ~(size_t)15;
        return p;
    };
    int* deg     = (int*)carve((size_t)2 * Nn * 4);
    int* cnt     = deg + Nn;
    int* starts  = (int*)carve((size_t)(Nn + 1) * 4);
    float* dinv  = (float*)carve((size_t)Nn * 4);
    int* src_s   = (int*)carve((size_t)Ee * 4);
    float* w_s   = (float*)carve((size_t)Ee * 4);
    float4* ea_s = (float4*)carve((size_t)Ee * 16);
    unsigned short* WThi = (unsigned short*)carve((size_t)17 * 16384 * 2);
    unsigned short* WTlo = (unsigned short*)carve((size_t)17 * 16384 * 2);
    float* hbuf  = (float*)carve((size_t)Nn * Hd * 4);
    float* obuf  = (float*)carve((size_t)Nn * Hd * 4);
    unsigned short* hb16 = (unsigned short*)carve((size_t)Nn * Hd * 2);
    unsigned short* pb0  = (unsigned short*)carve((size_t)Nn * Hd * 2);
    unsigned short* pb1  = (unsigned short*)carve((size_t)Nn * Hd * 2);
    unsigned short* pb2  = (unsigned short*)carve((size_t)Nn * Hd * 2);
    // aliases (dead before the hop phase): xp on pb0; xjs spans pb1+pb2
    float* xp  = (float*)pb0;   // 1.6 MB <= 12.8 MB
    float* xjs = (float*)pb1;   // 19.2 MB <= 25.6 MB (pb1+pb2 contiguous)

    zero_int_kernel<<<400, 256, 0, stream>>>(deg, 2 * Nn);
    count_kernel<<<(Ee + 255) / 256, 256, 0, stream>>>(col, deg);
    wconv_kernel<<<(17 * 16384 + 255) / 256, 256, 0, stream>>>(eW2, tagW, WThi, WTlo);
    xpack_kernel<<<(Nn + 255) / 256, 256, 0, stream>>>(x, xp);
    scan_kernel<<<1, 1024, 0, stream>>>(deg, starts, dinv);
    fill_kernel<<<(Ee + 255) / 256, 256, 0, stream>>>(row, col, starts, cnt, dinv, ea,
                                                      src_s, w_s, ea_s);
    xgather_kernel<<<(2 * Ee + 255) / 256, 256, 0, stream>>>(src_s, xp, xjs);
    // t = per-target sum of relu(layer1)  (into obuf fp32)
    edge_l1_kernel<<<6250, 256, 0, stream>>>(xp, xjs, ea_s, starts, eW1, eb1, obuf);
    // h0 = t @ W2 + deg*b2  (fp32 into hbuf, bf16 copy into hb16)
    const int gemm_grid = (Nn + 63) / 64;
    tag_gemm_mfma<<<gemm_grid, 256, 0, stream>>>(obuf, nullptr, nullptr, nullptr,
                                                 WThi, WTlo, eb2, deg,
                                                 hbuf, hb16, nullptr, nullptr, nullptr,
                                                 1, 0);

    for (int l = 0; l < Ld; ++l) {
        hop_kernel<<<12500, 256, 0, stream>>>(hb16, pb0, starts, src_s, w_s);
        hop_kernel<<<12500, 256, 0, stream>>>(pb0, pb1, starts, src_s, w_s);
        hop_kernel<<<12500, 256, 0, stream>>>(pb1, pb2, starts, src_s, w_s);
        int last = (l == Ld - 1);
        tag_gemm_mfma<<<gemm_grid, 256, 0, stream>>>(
            hbuf, pb0, pb1, pb2,
            WThi + (size_t)(1 + l * 4) * 16384, WTlo + (size_t)(1 + l * 4) * 16384,
            tagb + l * Hd, nullptr, obuf,
            last ? nullptr : hb16,
            last ? oW : nullptr, last ? ob : nullptr, last ? y : nullptr,
            4, last ? 0 : 1);
        float* t = hbuf; hbuf = obuf; obuf = t;
    }
}

// Round 13
// 838.042 us; speedup vs baseline: 1.6407x; 1.0195x over previous
//
#include <hip/hip_runtime.h>

#define Nn 50000
#define Ee 600000
#define Hd 128
#define Ld 4
#define Kd 3

typedef __attribute__((ext_vector_type(8))) short short8;
typedef __attribute__((ext_vector_type(4))) float float4v;

union U4 { uint4 u; short8 s; };

__device__ __forceinline__ unsigned bf16rne(float f) {
    unsigned u = __float_as_uint(f);
    return (u + 0x7fffu + ((u >> 16) & 1u)) >> 16;
}
__device__ __forceinline__ float bf16lo(unsigned v) { return __uint_as_float(v << 16); }
__device__ __forceinline__ float bf16hi(unsigned v) { return __uint_as_float(v & 0xffff0000u); }

__global__ void zero_int_kernel(int* __restrict__ p, int n) {
    int i = blockIdx.x * blockDim.x + threadIdx.x;
    int stride = gridDim.x * blockDim.x;
    for (; i < n; i += stride) p[i] = 0;
}

__global__ void count_kernel(const int* __restrict__ col, int* __restrict__ deg) {
    int e = blockIdx.x * blockDim.x + threadIdx.x;
    if (e < Ee) atomicAdd(&deg[col[e]], 1);
}

// Shfl-based exclusive scan.
__global__ void scan_kernel(const int* __restrict__ deg, int* __restrict__ starts,
                            float* __restrict__ dinv) {
    __shared__ int wsum[16];
    __shared__ int carry_s;
    int tid = threadIdx.x;
    int lane = tid & 63, w = tid >> 6;
    if (tid == 0) carry_s = 0;
    __syncthreads();
    for (int base = 0; base < Nn; base += 1024) {
        int i = base + tid;
        int v = (i < Nn) ? deg[i] : 0;
        if (i < Nn) dinv[i] = (v > 0) ? rsqrtf((float)v) : 0.0f;
        int s = v;
#pragma unroll
        for (int off = 1; off < 64; off <<= 1) {
            int t = __shfl_up(s, off);
            if (lane >= off) s += t;
        }
        if (lane == 63) wsum[w] = s;
        __syncthreads();
        if (w == 0) {
            int ws = (lane < 16) ? wsum[lane] : 0;
#pragma unroll
            for (int off = 1; off < 16; off <<= 1) {
                int t = __shfl_up(ws, off);
                if (lane >= off) ws += t;
            }
            if (lane < 16) wsum[lane] = ws;
        }
        __syncthreads();
        int woff = (w > 0) ? wsum[w - 1] : 0;
        int carry = carry_s;
        if (i < Nn) starts[i] = carry + woff + s - v;
        __syncthreads();
        if (tid == 1023) carry_s = carry + wsum[15];
    }
    __syncthreads();
    if (threadIdx.x == 0) starts[Nn] = carry_s;
}

// CSR fill; writes ea_s (slot-ordered edge attrs) directly.
__global__ void fill_kernel(const int* __restrict__ row, const int* __restrict__ col,
                            const int* __restrict__ starts, int* __restrict__ cnt,
                            const float* __restrict__ dinv, const float* __restrict__ ea,
                            int* __restrict__ src_s, float* __restrict__ w_s,
                            float4* __restrict__ ea_s) {
    int e = blockIdx.x * blockDim.x + threadIdx.x;
    if (e < Ee) {
        int c = col[e], r = row[e];
        float4 ev = *(const float4*)&ea[(size_t)e * 4];
        int slot = starts[c] + atomicAdd(&cnt[c], 1);
        src_s[slot] = r;
        w_s[slot] = dinv[r] * dinv[c];
        ea_s[slot] = ev;
    }
}

// x [N][7] -> padded aligned xp [N][8] (pad = 0)
__global__ void xpack_kernel(const float* __restrict__ x, float* __restrict__ xp) {
    int i = blockIdx.x * blockDim.x + threadIdx.x;
    if (i < Nn) {
        float4 a = make_float4(x[i * 7], x[i * 7 + 1], x[i * 7 + 2], x[i * 7 + 3]);
        float4 b = make_float4(x[i * 7 + 4], x[i * 7 + 5], x[i * 7 + 6], 0.0f);
        *(float4*)&xp[i * 8] = a;
        *(float4*)&xp[i * 8 + 4] = b;
    }
}

// Decoupled gather: xjs[slot] = xp[src_s[slot]] (32 B rows, slot-ordered out).
__global__ void xgather_kernel(const int* __restrict__ src_s, const float* __restrict__ xp,
                               float* __restrict__ xjs) {
    int gid = blockIdx.x * blockDim.x + threadIdx.x;
    int slot = gid >> 1, part = gid & 1;
    if (slot < Ee) {
        int src = src_s[slot];
        float4 v = *(const float4*)&xp[(size_t)src * 8 + part * 4];
        *(float4*)&xjs[(size_t)slot * 8 + part * 4] = v;
    }
}

// 17 weight matrices [k][n] fp32 -> FRAGMENT-SWIZZLED bf16 hi/lo planes.
__global__ void wconv_kernel(const float* __restrict__ eW2, const float* __restrict__ tagW,
                             unsigned short* __restrict__ WThi,
                             unsigned short* __restrict__ WTlo) {
    int id = blockIdx.x * blockDim.x + threadIdx.x;
    if (id >= 17 * 16384) return;
    int m = id >> 14;
    int rem = id & 16383;
    int n = rem >> 7, k = rem & 127;
    const float* src = (m == 0) ? eW2 : tagW + (size_t)(m - 1) * 16384;
    float f = src[k * Hd + n];
    unsigned h = bf16rne(f);
    float r = f - __uint_as_float(h << 16);
    int kc = k >> 5, quad = (k >> 3) & 3, j = k & 7;
    int nt = n >> 4, l15 = n & 15;
    int lane = quad * 16 + l15;
    int idx = (m << 14) + (((kc * 8 + nt) * 64) + lane) * 8 + j;
    WThi[idx] = (unsigned short)h;
    WTlo[idx] = (unsigned short)bf16rne(r);
}

// Layer-1-only edge pass v3 (pure streaming); emits t in bf16.
__global__ __launch_bounds__(256) void edge_l1_kernel(
    const float* __restrict__ xp, const float* __restrict__ xjs,
    const float4* __restrict__ ea_s,
    const int* __restrict__ starts,
    const float* __restrict__ eW1, const float* __restrict__ eb1,
    unsigned short* __restrict__ tout) {
    int lane = threadIdx.x & 63;
    float w1x[18], w1y[18];
#pragma unroll
    for (int j = 0; j < 18; ++j) {
        w1x[j] = eW1[j * Hd + lane];
        w1y[j] = eW1[j * Hd + lane + 64];
    }
    float b1x = eb1[lane], b1y = eb1[lane + 64];
    int wid = (blockIdx.x * 256 + threadIdx.x) >> 6;
    int nw = (gridDim.x * 256) >> 6;
    for (int node = wid; node < Nn; node += nw) {
        int s0 = starts[node], s1 = starts[node + 1];
        float4 p0 = *(const float4*)&xp[node * 8];
        float4 p1 = *(const float4*)&xp[node * 8 + 4];
        float prex = b1x + p0.x * w1x[0] + p0.y * w1x[1] + p0.z * w1x[2] + p0.w * w1x[3]
                   + p1.x * w1x[4] + p1.y * w1x[5] + p1.z * w1x[6];
        float prey = b1y + p0.x * w1y[0] + p0.y * w1y[1] + p0.z * w1y[2] + p0.w * w1y[3]
                   + p1.x * w1y[4] + p1.y * w1y[5] + p1.z * w1y[6];
        float accx = 0.0f, accy = 0.0f;
        int slot = s0;
        for (; slot + 2 <= s1; slot += 2) {
            float4 a0 = *(const float4*)&xjs[(size_t)slot * 8];
            float4 a1 = *(const float4*)&xjs[(size_t)slot * 8 + 4];
            float4 b0 = *(const float4*)&xjs[(size_t)(slot + 1) * 8];
            float4 b1v = *(const float4*)&xjs[(size_t)(slot + 1) * 8 + 4];
            float4 eA = ea_s[slot], eB = ea_s[slot + 1];
            float u0 = prex + a0.x * w1x[7] + a0.y * w1x[8] + a0.z * w1x[9] + a0.w * w1x[10]
                     + a1.x * w1x[11] + a1.y * w1x[12] + a1.z * w1x[13]
                     + eA.x * w1x[14] + eA.y * w1x[15] + eA.z * w1x[16] + eA.w * w1x[17];
            float u1 = prey + a0.x * w1y[7] + a0.y * w1y[8] + a0.z * w1y[9] + a0.w * w1y[10]
                     + a1.x * w1y[11] + a1.y * w1y[12] + a1.z * w1y[13]
                     + eA.x * w1y[14] + eA.y * w1y[15] + eA.z * w1y[16] + eA.w * w1y[17];
            float v0 = prex + b0.x * w1x[7] + b0.y * w1x[8] + b0.z * w1x[9] + b0.w * w1x[10]
                     + b1v.x * w1x[11] + b1v.y * w1x[12] + b1v.z * w1x[13]
                     + eB.x * w1x[14] + eB.y * w1x[15] + eB.z * w1x[16] + eB.w * w1x[17];
            float v1 = prey + b0.x * w1y[7] + b0.y * w1y[8] + b0.z * w1y[9] + b0.w * w1y[10]
                     + b1v.x * w1y[11] + b1v.y * w1y[12] + b1v.z * w1y[13]
                     + eB.x * w1y[14] + eB.y * w1y[15] + eB.z * w1y[16] + eB.w * w1y[17];
            accx += fmaxf(u0, 0.0f) + fmaxf(v0, 0.0f);
            accy += fmaxf(u1, 0.0f) + fmaxf(v1, 0.0f);
        }
        if (slot < s1) {
            float4 a0 = *(const float4*)&xjs[(size_t)slot * 8];
            float4 a1 = *(const float4*)&xjs[(size_t)slot * 8 + 4];
            float4 eA = ea_s[slot];
            float u0 = prex + a0.x * w1x[7] + a0.y * w1x[8] + a0.z * w1x[9] + a0.w * w1x[10]
                     + a1.x * w1x[11] + a1.y * w1x[12] + a1.z * w1x[13]
                     + eA.x * w1x[14] + eA.y * w1x[15] + eA.z * w1x[16] + eA.w * w1x[17];
            float u1 = prey + a0.x * w1y[7] + a0.y * w1y[8] + a0.z * w1y[9] + a0.w * w1y[10]
                     + a1.x * w1y[11] + a1.y * w1y[12] + a1.z * w1y[13]
                     + eA.x * w1y[14] + eA.y * w1y[15] + eA.z * w1y[16] + eA.w * w1y[17];
            accx += fmaxf(u0, 0.0f);
            accy += fmaxf(u1, 0.0f);
        }
        tout[node * Hd + lane] = (unsigned short)bf16rne(accx);
        tout[node * Hd + lane + 64] = (unsigned short)bf16rne(accy);
    }
}

// MFMA multi-source GEMM, all-bf16 A path (2 mfma/k-step uniform), LDS-free
// K-loop, fragment-swizzled W. Output is bf16 only (Cb16); when yout is
// non-null (final layer) the head y = C @ oW + ob is fused and Cb16 skipped.
__global__ __launch_bounds__(256, 2) void tag_gemm_mfma(
    const unsigned short* __restrict__ P0,
    const unsigned short* __restrict__ Pb1, const unsigned short* __restrict__ Pb2,
    const unsigned short* __restrict__ Pb3,
    const unsigned short* __restrict__ WThi, const unsigned short* __restrict__ WTlo,
    const float* __restrict__ bias, const int* __restrict__ rowdeg,
    unsigned short* __restrict__ Cb16,
    const float* __restrict__ oW, const float* __restrict__ ob,
    float* __restrict__ yout, int nsrc, int reluflag) {
    __shared__ float Cl[64 * 133];
    __shared__ float oWs[256];
    __shared__ float obs[2];
    const int tid = threadIdx.x;
    const int lane = tid & 63;
    const int wv = tid >> 6;
    const int l15 = lane & 15;
    const int quad = lane >> 4;
    const int rowbase = blockIdx.x * 64;
    const int arow = min(rowbase + wv * 16 + l15, Nn - 1);
    if (yout) {
        oWs[tid] = oW[tid & 255];
        if (tid < 2) obs[tid] = ob[tid];
    }

    float4v acc[8];
#pragma unroll
    for (int nt = 0; nt < 8; ++nt) acc[nt] = (float4v)0.0f;

#pragma unroll 1
    for (int g = 0; g < nsrc; ++g) {
        const unsigned short* Pb = (g == 0) ? P0 : (g == 1) ? Pb1 : (g == 2) ? Pb2 : Pb3;
        const unsigned short* Whg = WThi + (size_t)g * 16384;
        const unsigned short* Wlg = WTlo + (size_t)g * 16384;
#pragma unroll
        for (int kc = 0; kc < 4; ++kc) {
            U4 ab;
            ab.u = *(const uint4*)&Pb[(size_t)arow * Hd + kc * 32 + quad * 8];
            const unsigned short* whp = Whg + (size_t)(kc * 8) * 512 + lane * 8;
            const unsigned short* wlp = Wlg + (size_t)(kc * 8) * 512 + lane * 8;
#pragma unroll
            for (int nt = 0; nt < 8; ++nt) {
                U4 wh, wl;
                wh.u = *(const uint4*)&whp[nt * 512];
                wl.u = *(const uint4*)&wlp[nt * 512];
                acc[nt] = __builtin_amdgcn_mfma_f32_16x16x32_bf16(ab.s, wh.s, acc[nt], 0, 0, 0);
                acc[nt] = __builtin_amdgcn_mfma_f32_16x16x32_bf16(ab.s, wl.s, acc[nt], 0, 0, 0);
            }
        }
    }
#pragma unroll
    for (int nt = 0; nt < 8; ++nt)
#pragma unroll
        for (int reg = 0; reg < 4; ++reg)
            Cl[(wv * 16 + quad * 4 + reg) * 133 + nt * 16 + l15] = acc[nt][reg];
    __syncthreads();
#pragma unroll
    for (int i = 0; i < 8; ++i) {
        int s = tid + i * 256;
        int r = s >> 5, c4 = (s & 31) * 4;
        int grow = rowbase + r;
        if (grow < Nn) {
            float4 v = *(const float4*)&Cl[r * 133 + c4];
            float4 bv = *(const float4*)&bias[c4];
            float bs = rowdeg ? (float)rowdeg[grow] : 1.0f;
            v.x += bs * bv.x; v.y += bs * bv.y; v.z += bs * bv.z; v.w += bs * bv.w;
            if (reluflag) {
                v.x = fmaxf(v.x, 0.0f); v.y = fmaxf(v.y, 0.0f);
                v.z = fmaxf(v.z, 0.0f); v.w = fmaxf(v.w, 0.0f);
            }
            if (yout) {
                *(float4*)&Cl[r * 133 + c4] = v;  // keep for the fused head
            } else {
                uint2 p;
                p.x = bf16rne(v.x) | (bf16rne(v.y) << 16);
                p.y = bf16rne(v.z) | (bf16rne(v.w) << 16);
                *(uint2*)&Cb16[(size_t)grow * Hd + c4] = p;
            }
        }
    }
    if (yout) {
        __syncthreads();
        if (tid < 64) {
            int grow = rowbase + tid;
            if (grow < Nn) {
                float a0 = obs[0], a1 = obs[1];
#pragma unroll
                for (int c = 0; c < Hd; c += 4) {
                    float4 t = *(const float4*)&Cl[tid * 133 + c];
                    a0 += t.x * oWs[2 * c] + t.y * oWs[2 * c + 2]
                        + t.z * oWs[2 * c + 4] + t.w * oWs[2 * c + 6];
                    a1 += t.x * oWs[2 * c + 1] + t.y * oWs[2 * c + 3]
                        + t.z * oWs[2 * c + 5] + t.w * oWs[2 * c + 7];
                }
                *(float2*)&yout[(size_t)grow * 2] = make_float2(a0, a1);
            }
        }
    }
}

// bf16 hop v5: quarter-wave split, single uniform stride-4 loop.
__global__ void hop_kernel(const unsigned short* __restrict__ pin,
                           unsigned short* __restrict__ pout,
                           const int* __restrict__ starts, const int* __restrict__ src_s,
                           const float* __restrict__ w_s) {
    int lane = threadIdx.x & 63;
    int q = lane >> 4, r = lane & 15;
    int node = (blockIdx.x * blockDim.x + threadIdx.x) >> 6;
    if (node >= Nn) return;
    int s0 = starts[node], s1 = starts[node + 1];
    float a[8];
#pragma unroll
    for (int i = 0; i < 8; ++i) a[i] = 0.0f;
    for (int slot = s0 + q; slot < s1; slot += 4) {
        int src = src_s[slot];
        float w = w_s[slot];
        uint4 v = *(const uint4*)&pin[(size_t)src * Hd + r * 8];
        a[0] += w * bf16lo(v.x); a[1] += w * bf16hi(v.x);
        a[2] += w * bf16lo(v.y); a[3] += w * bf16hi(v.y);
        a[4] += w * bf16lo(v.z); a[5] += w * bf16hi(v.z);
        a[6] += w * bf16lo(v.w); a[7] += w * bf16hi(v.w);
    }
#pragma unroll
    for (int i = 0; i < 8; ++i) {
        a[i] += __shfl_xor(a[i], 16);
        a[i] += __shfl_xor(a[i], 32);
    }
    if (q == 0) {
        uint4 o;
        o.x = bf16rne(a[0]) | (bf16rne(a[1]) << 16);
        o.y = bf16rne(a[2]) | (bf16rne(a[3]) << 16);
        o.z = bf16rne(a[4]) | (bf16rne(a[5]) << 16);
        o.w = bf16rne(a[6]) | (bf16rne(a[7]) << 16);
        *(uint4*)&pout[(size_t)node * Hd + r * 8] = o;
    }
}

extern "C" void kernel_launch(void* const* d_in, const int* in_sizes, int n_in,
                              void* d_out, int out_size, void* d_ws, size_t ws_size,
                              hipStream_t stream) {
    const float* x    = (const float*)d_in[0];
    const int*   ei   = (const int*)d_in[1];
    const float* ea   = (const float*)d_in[2];
    const float* eW1  = (const float*)d_in[3];
    const float* eb1  = (const float*)d_in[4];
    const float* eW2  = (const float*)d_in[5];
    const float* eb2  = (const float*)d_in[6];
    const float* tagW = (const float*)d_in[7];
    const float* tagb = (const float*)d_in[8];
    const float* oW   = (const float*)d_in[9];
    const float* ob   = (const float*)d_in[10];
    float* y = (float*)d_out;
    const int* row = ei;        // source
    const int* col = ei + Ee;   // target

    char* wp = (char*)d_ws;
    auto carve = [&](size_t bytes) -> char* {
        char* p = wp;
        wp += (bytes + 15) & ~(size_t)15;
        return p;
    };
    int* deg     = (int*)carve((size_t)2 * Nn * 4);
    int* cnt     = deg + Nn;
    int* starts  = (int*)carve((size_t)(Nn + 1) * 4);
    float* dinv  = (float*)carve((size_t)Nn * 4);
    int* src_s   = (int*)carve((size_t)Ee * 4);
    float* w_s   = (float*)carve((size_t)Ee * 4);
    float4* ea_s = (float4*)carve((size_t)Ee * 16);
    unsigned short* WThi = (unsigned short*)carve((size_t)17 * 16384 * 2);
    unsigned short* WTlo = (unsigned short*)carve((size_t)17 * 16384 * 2);
    unsigned short* t16  = (unsigned short*)carve((size_t)Nn * Hd * 2);
    unsigned short* h16a = (unsigned short*)carve((size_t)Nn * Hd * 2);
    unsigned short* h16b = (unsigned short*)carve((size_t)Nn * Hd * 2);
    unsigned short* pb0  = (unsigned short*)carve((size_t)Nn * Hd * 2);
    unsigned short* pb1  = (unsigned short*)carve((size_t)Nn * Hd * 2);
    unsigned short* pb2  = (unsigned short*)carve((size_t)Nn * Hd * 2);
    // aliases (dead before their regions are first written):
    float* xp  = (float*)pb2;   // 1.6 MB; pb2 first written at hop k=3
    float* xjs = (float*)h16b;  // 19.2 MB spans h16b+pb0; first written layer-0 gemm/hop

    zero_int_kernel<<<400, 256, 0, stream>>>(deg, 2 * Nn);
    count_kernel<<<(Ee + 255) / 256, 256, 0, stream>>>(col, deg);
    wconv_kernel<<<(17 * 16384 + 255) / 256, 256, 0, stream>>>(eW2, tagW, WThi, WTlo);
    xpack_kernel<<<(Nn + 255) / 256, 256, 0, stream>>>(x, xp);
    scan_kernel<<<1, 1024, 0, stream>>>(deg, starts, dinv);
    fill_kernel<<<(Ee + 255) / 256, 256, 0, stream>>>(row, col, starts, cnt, dinv, ea,
                                                      src_s, w_s, ea_s);
    xgather_kernel<<<(2 * Ee + 255) / 256, 256, 0, stream>>>(src_s, xp, xjs);
    // t = per-target sum of relu(layer1), bf16 (into t16)
    edge_l1_kernel<<<6250, 256, 0, stream>>>(xp, xjs, ea_s, starts, eW1, eb1, t16);
    // h0 = t @ W2 + deg*b2  (bf16 into h16a)
    const int gemm_grid = (Nn + 63) / 64;
    tag_gemm_mfma<<<gemm_grid, 256, 0, stream>>>(t16, nullptr, nullptr, nullptr,
                                                 WThi, WTlo, eb2, deg, h16a,
                                                 nullptr, nullptr, nullptr, 1, 0);

    unsigned short* hin = h16a;
    unsigned short* hout = h16b;
    for (int l = 0; l < Ld; ++l) {
        hop_kernel<<<12500, 256, 0, stream>>>(hin, pb0, starts, src_s, w_s);
        hop_kernel<<<12500, 256, 0, stream>>>(pb0, pb1, starts, src_s, w_s);
        hop_kernel<<<12500, 256, 0, stream>>>(pb1, pb2, starts, src_s, w_s);
        int last = (l == Ld - 1);
        tag_gemm_mfma<<<gemm_grid, 256, 0, stream>>>(
            hin, pb0, pb1, pb2,
            WThi + (size_t)(1 + l * 4) * 16384, WTlo + (size_t)(1 + l * 4) * 16384,
            tagb + l * Hd, nullptr, last ? nullptr : hout,
            last ? oW : nullptr, last ? ob : nullptr, last ? y : nullptr,
            4, last ? 0 : 1);
        unsigned short* t = hin; hin = hout; hout = t;
    }
}